// Round 1
// baseline (3125.246 us; speedup 1.0000x reference)
//
#include <hip/hip_runtime.h>
#include <hip/hip_bf16.h>

// Problem constants
#define S_LEN   2048
#define HID     2560
#define NH      32
#define NKV     8
#define HD      128
#define QDIM    (NH*HD)    // 4096
#define KVDIM   (NKV*HD)   // 1024

// ---------------------------------------------------------------------------
// GEMM: C[M,N] = A[M,Kd] * B[N,Kd]^T   (all row-major, fp32)
// 128x128 block tile, BK=16, 256 threads, 8x8 micro-tile per thread.
// LDS tiles stored k-major (As[k][m]) so inner-loop reads are float4.
// ---------------------------------------------------------------------------
__global__ __launch_bounds__(256) void gemm_abt(
    const float* __restrict__ A, const float* __restrict__ B,
    float* __restrict__ C, int M, int N, int Kd)
{
    __shared__ float As[16][132];
    __shared__ float Bs[16][132];
    const int tid = threadIdx.x;
    const int tx = tid & 15, ty = tid >> 4;
    const int rowA0 = blockIdx.y * 128;
    const int rowB0 = blockIdx.x * 128;

    float acc[8][8];
#pragma unroll
    for (int i = 0; i < 8; i++)
#pragma unroll
        for (int j = 0; j < 8; j++) acc[i][j] = 0.f;

    for (int k0 = 0; k0 < Kd; k0 += 16) {
        // load 128x16 tiles of A and B (transposed into k-major LDS)
#pragma unroll
        for (int i = 0; i < 2; i++) {
            int f4 = tid + i * 256;      // 0..511
            int r  = f4 >> 2;            // 0..127
            int c4 = f4 & 3;             // 0..3 (float4 col)
            const float4 av = *(const float4*)(A + (size_t)(rowA0 + r) * Kd + k0 + c4 * 4);
            const float4 bv = *(const float4*)(B + (size_t)(rowB0 + r) * Kd + k0 + c4 * 4);
            As[c4*4+0][r] = av.x; As[c4*4+1][r] = av.y; As[c4*4+2][r] = av.z; As[c4*4+3][r] = av.w;
            Bs[c4*4+0][r] = bv.x; Bs[c4*4+1][r] = bv.y; Bs[c4*4+2][r] = bv.z; Bs[c4*4+3][r] = bv.w;
        }
        __syncthreads();
#pragma unroll
        for (int kk = 0; kk < 16; kk++) {
            float4 a0 = *(const float4*)&As[kk][ty*8];
            float4 a1 = *(const float4*)&As[kk][ty*8+4];
            float4 b0 = *(const float4*)&Bs[kk][tx*8];
            float4 b1 = *(const float4*)&Bs[kk][tx*8+4];
            float a[8] = {a0.x,a0.y,a0.z,a0.w,a1.x,a1.y,a1.z,a1.w};
            float b[8] = {b0.x,b0.y,b0.z,b0.w,b1.x,b1.y,b1.z,b1.w};
#pragma unroll
            for (int i = 0; i < 8; i++)
#pragma unroll
                for (int j = 0; j < 8; j++) acc[i][j] += a[i]*b[j];
        }
        __syncthreads();
    }
#pragma unroll
    for (int i = 0; i < 8; i++) {
        float* crow = C + (size_t)(rowA0 + ty*8 + i) * N + rowB0 + tx*8;
        *(float4*)(crow)     = make_float4(acc[i][0], acc[i][1], acc[i][2], acc[i][3]);
        *(float4*)(crow + 4) = make_float4(acc[i][4], acc[i][5], acc[i][6], acc[i][7]);
    }
}

// ---------------------------------------------------------------------------
// RMSNorm (per 128-d head vector) + RoPE, in place.
// One wave per (s, head) vector; lane l handles elements l and l+64.
// ---------------------------------------------------------------------------
__global__ __launch_bounds__(256) void rmsnorm_rope(
    float* __restrict__ X, const float* __restrict__ w,
    const float* __restrict__ ct, const float* __restrict__ st, int nheads)
{
    int wid  = (blockIdx.x * blockDim.x + threadIdx.x) >> 6;
    int lane = threadIdx.x & 63;
    int s = wid / nheads;
    int h = wid - s * nheads;
    float* x = X + (size_t)s * (nheads * HD) + h * HD;

    float x1 = x[lane];
    float x2 = x[lane + 64];
    float ss = x1*x1 + x2*x2;
#pragma unroll
    for (int off = 32; off > 0; off >>= 1) ss += __shfl_xor(ss, off, 64);
    float r = rsqrtf(ss * (1.0f/128.0f) + 1e-6f);
    float n1 = x1 * r * w[lane];
    float n2 = x2 * r * w[lane + 64];
    float c1 = ct[s*HD + lane],      s1 = st[s*HD + lane];
    float c2 = ct[s*HD + lane + 64], s2 = st[s*HD + lane + 64];
    // rotate_half: out[d]=n[d]*c[d]-n[d+64]*s[d] (d<64); out[d]=n[d]*c[d]+n[d-64]*s[d] (d>=64)
    x[lane]      = n1*c1 - n2*s1;
    x[lane + 64] = n2*c2 + n1*s2;
}

// ---------------------------------------------------------------------------
// Flash attention, fp32, causal, GQA (4 q-heads per kv-head).
// One block = (64-row Q tile, one q-head). KV streamed in 32-row tiles.
// 256 threads as 16x16: scores thread (tx,ty) -> rows ty*4+i, cols tx*2+j;
// PV thread -> rows ty*4+i, dims tx*8+j.
// ---------------------------------------------------------------------------
__global__ __launch_bounds__(256) void flash_attn(
    const float* __restrict__ Q, const float* __restrict__ K,
    const float* __restrict__ V, float* __restrict__ O)
{
    const int qb  = blockIdx.x;
    const int h   = blockIdx.y;
    const int kvh = h >> 2;
    const int tid = threadIdx.x;
    const int tx = tid & 15, ty = tid >> 4;

    __shared__ float Qs[64][132];
    __shared__ float Ks[32][132];
    __shared__ float Vs[32][132];
    __shared__ float Ss[64][33];
    __shared__ float m_s[64], l_s[64], al_s[64];

    // load Q tile (64 x 128)
    {
        const float* qbase = Q + (size_t)qb * 64 * QDIM + h * HD;
#pragma unroll
        for (int i = 0; i < 8; i++) {
            int f4 = tid + i * 256;          // 0..2047
            int r  = f4 >> 5, c4 = f4 & 31;  // 32 float4 per row
            *(float4*)&Qs[r][c4*4] = *(const float4*)(qbase + (size_t)r * QDIM + c4 * 4);
        }
    }
    if (tid < 64) { m_s[tid] = -1e30f; l_s[tid] = 0.f; }

    float acc[4][8];
#pragma unroll
    for (int i = 0; i < 4; i++)
#pragma unroll
        for (int j = 0; j < 8; j++) acc[i][j] = 0.f;

    const int q0 = qb * 64;
    const int ntiles = (q0 + 64) / 32;
    const float scale = 0.08838834764831845f;  // 128^-0.5

    for (int t = 0; t < ntiles; t++) {
        const int c0 = t * 32;
        __syncthreads();   // previous iteration done with Ks/Vs/Ss
        {
            const float* kbase = K + (size_t)c0 * KVDIM + kvh * HD;
            const float* vbase = V + (size_t)c0 * KVDIM + kvh * HD;
#pragma unroll
            for (int i = 0; i < 4; i++) {
                int f4 = tid + i * 256;          // 0..1023
                int r  = f4 >> 5, c4 = f4 & 31;
                *(float4*)&Ks[r][c4*4] = *(const float4*)(kbase + (size_t)r * KVDIM + c4 * 4);
                *(float4*)&Vs[r][c4*4] = *(const float4*)(vbase + (size_t)r * KVDIM + c4 * 4);
            }
        }
        __syncthreads();

        // scores 64x32
        float sc[4][2];
#pragma unroll
        for (int i = 0; i < 4; i++) { sc[i][0] = 0.f; sc[i][1] = 0.f; }
        for (int k4 = 0; k4 < 32; k4++) {
            float4 qv[4], kv[2];
#pragma unroll
            for (int i = 0; i < 4; i++) qv[i] = *(const float4*)&Qs[ty*4+i][k4*4];
#pragma unroll
            for (int j = 0; j < 2; j++) kv[j] = *(const float4*)&Ks[tx*2+j][k4*4];
#pragma unroll
            for (int i = 0; i < 4; i++)
#pragma unroll
                for (int j = 0; j < 2; j++)
                    sc[i][j] += qv[i].x*kv[j].x + qv[i].y*kv[j].y
                              + qv[i].z*kv[j].z + qv[i].w*kv[j].w;
        }
#pragma unroll
        for (int i = 0; i < 4; i++) {
            int r = ty*4 + i, grow = q0 + r;
#pragma unroll
            for (int j = 0; j < 2; j++) {
                int c = tx*2 + j, gcol = c0 + c;
                Ss[r][c] = (gcol <= grow) ? sc[i][j] * scale : -1e30f;
            }
        }
        __syncthreads();

        // online softmax, one thread per row
        if (tid < 64) {
            int r = tid;
            float m_old = m_s[r];
            float mx = m_old;
#pragma unroll
            for (int c = 0; c < 32; c++) mx = fmaxf(mx, Ss[r][c]);
            float l_add = 0.f;
#pragma unroll
            for (int c = 0; c < 32; c++) {
                float p = __expf(Ss[r][c] - mx);
                Ss[r][c] = p;
                l_add += p;
            }
            float alpha = __expf(m_old - mx);
            m_s[r] = mx;
            l_s[r] = l_s[r] * alpha + l_add;
            al_s[r] = alpha;
        }
        __syncthreads();

        // PV accumulate
#pragma unroll
        for (int i = 0; i < 4; i++) {
            float a = al_s[ty*4 + i];
#pragma unroll
            for (int j = 0; j < 8; j++) acc[i][j] *= a;
        }
        for (int c = 0; c < 32; c++) {
            float4 v0 = *(const float4*)&Vs[c][tx*8];
            float4 v1 = *(const float4*)&Vs[c][tx*8+4];
#pragma unroll
            for (int i = 0; i < 4; i++) {
                float p = Ss[ty*4 + i][c];
                acc[i][0] += p * v0.x; acc[i][1] += p * v0.y;
                acc[i][2] += p * v0.z; acc[i][3] += p * v0.w;
                acc[i][4] += p * v1.x; acc[i][5] += p * v1.y;
                acc[i][6] += p * v1.z; acc[i][7] += p * v1.w;
            }
        }
    }

    // epilogue: O[q0+r][h*128 + tx*8 .. +7] = acc / l
#pragma unroll
    for (int i = 0; i < 4; i++) {
        int r = ty*4 + i;
        float inv = 1.0f / l_s[r];
        float* orow = O + (size_t)(q0 + r) * QDIM + h * HD + tx * 8;
        *(float4*)(orow)     = make_float4(acc[i][0]*inv, acc[i][1]*inv, acc[i][2]*inv, acc[i][3]*inv);
        *(float4*)(orow + 4) = make_float4(acc[i][4]*inv, acc[i][5]*inv, acc[i][6]*inv, acc[i][7]*inv);
    }
}

// ---------------------------------------------------------------------------
extern "C" void kernel_launch(void* const* d_in, const int* in_sizes, int n_in,
                              void* d_out, int out_size, void* d_ws, size_t ws_size,
                              hipStream_t stream)
{
    const float* hs   = (const float*)d_in[0];
    const float* cosb = (const float*)d_in[1];
    const float* sinb = (const float*)d_in[2];
    const float* Wq   = (const float*)d_in[3];
    const float* Wk   = (const float*)d_in[4];
    const float* Wv   = (const float*)d_in[5];
    const float* Wo   = (const float*)d_in[6];
    const float* qw   = (const float*)d_in[7];
    const float* kw   = (const float*)d_in[8];
    float* out = (float*)d_out;

    float* Qb = (float*)d_ws;                       // 2048 x 4096
    float* Kb = Qb + (size_t)S_LEN * QDIM;          // 2048 x 1024
    float* Vb = Kb + (size_t)S_LEN * KVDIM;         // 2048 x 1024
    float* Cb = Vb + (size_t)S_LEN * KVDIM;         // 2048 x 4096 (context)

    dim3 blk(256);
    // projections
    gemm_abt<<<dim3(QDIM/128,  S_LEN/128), blk, 0, stream>>>(hs, Wq, Qb, S_LEN, QDIM,  HID);
    gemm_abt<<<dim3(KVDIM/128, S_LEN/128), blk, 0, stream>>>(hs, Wk, Kb, S_LEN, KVDIM, HID);
    gemm_abt<<<dim3(KVDIM/128, S_LEN/128), blk, 0, stream>>>(hs, Wv, Vb, S_LEN, KVDIM, HID);
    // norm + rope
    rmsnorm_rope<<<S_LEN*NH/4,  256, 0, stream>>>(Qb, qw, cosb, sinb, NH);
    rmsnorm_rope<<<S_LEN*NKV/4, 256, 0, stream>>>(Kb, kw, cosb, sinb, NKV);
    // attention
    flash_attn<<<dim3(S_LEN/64, NH), blk, 0, stream>>>(Qb, Kb, Vb, Cb);
    // output projection
    gemm_abt<<<dim3(HID/128, S_LEN/128), blk, 0, stream>>>(Cb, Wo, out, S_LEN, HID, QDIM);
}

// Round 2
// 736.284 us; speedup vs baseline: 4.2446x; 4.2446x over previous
//
#include <hip/hip_runtime.h>

// Problem constants
#define S_LEN   2048
#define HID     2560
#define NH      32
#define NKV     8
#define HD      128
#define QDIM    (NH*HD)    // 4096
#define KVDIM   (NKV*HD)   // 1024

typedef __attribute__((ext_vector_type(8))) short short8;   // 8 bf16 (4 VGPRs)
typedef __attribute__((ext_vector_type(4))) float f32x4;    // MFMA C/D frag

__device__ __forceinline__ unsigned short f2bf(float f) {
    unsigned u = __float_as_uint(f);
    u += 0x7fffu + ((u >> 16) & 1u);        // round-to-nearest-even
    return (unsigned short)(u >> 16);
}
__device__ __forceinline__ float bf2f(unsigned short s) {
    return __uint_as_float(((unsigned)s) << 16);
}
__device__ __forceinline__ void gload16(const void* g, void* l) {
    __builtin_amdgcn_global_load_lds(
        (const __attribute__((address_space(1))) unsigned int*)g,
        (__attribute__((address_space(3))) unsigned int*)l, 16, 0, 0);
}

// ---------------------------------------------------------------------------
// fp32 -> bf16 elementwise convert (vectorized x4)
// ---------------------------------------------------------------------------
__global__ __launch_bounds__(256) void cvt_f32_bf16(
    const float* __restrict__ s, unsigned short* __restrict__ d, int n4)
{
    int i = blockIdx.x * 256 + threadIdx.x;
    if (i >= n4) return;
    float4 v = ((const float4*)s)[i];
    ushort4 o;
    o.x = f2bf(v.x); o.y = f2bf(v.y); o.z = f2bf(v.z); o.w = f2bf(v.w);
    ((ushort4*)d)[i] = o;
}

// ---------------------------------------------------------------------------
// bf16 MFMA GEMM: C[M,N] = A[M,K] * B[N,K]^T, m97 structure.
// 128x128 tile, BK=32, 256 threads (4 waves, each 64x64 = 4x4 MFMA tiles).
// A,B staged via global_load_lds width=16 (LDS layout unpadded [128][32]).
// Output either fp32 (Cf) or bf16 (Cb).
// ---------------------------------------------------------------------------
__global__ __launch_bounds__(256) void gemm_bf16(
    const unsigned short* __restrict__ A, const unsigned short* __restrict__ B,
    float* __restrict__ Cf, unsigned short* __restrict__ Cb, int N, int Kd)
{
    __shared__ unsigned short As[128*32];
    __shared__ unsigned short Bs[128*32];
    const int tid = threadIdx.x;
    const int w = tid >> 6, lane = tid & 63;
    const int l15 = lane & 15, l4 = lane >> 4;
    const int rowA0 = blockIdx.y * 128, rowB0 = blockIdx.x * 128;
    const int wr = (w >> 1) * 64, wc = (w & 1) * 64;

    const f32x4 zero = {0.f, 0.f, 0.f, 0.f};
    f32x4 acc[4][4];
#pragma unroll
    for (int i = 0; i < 4; i++)
#pragma unroll
        for (int j = 0; j < 4; j++) acc[i][j] = zero;

    const int c0c = tid, c1c = tid + 256;   // 16B chunk ids (512 per 8KB tile)

    for (int k0 = 0; k0 < Kd; k0 += 32) {
        __syncthreads();
        gload16(A + (size_t)(rowA0 + (c0c>>2))*Kd + k0 + (c0c&3)*8, &As[c0c*8]);
        gload16(A + (size_t)(rowA0 + (c1c>>2))*Kd + k0 + (c1c&3)*8, &As[c1c*8]);
        gload16(B + (size_t)(rowB0 + (c0c>>2))*Kd + k0 + (c0c&3)*8, &Bs[c0c*8]);
        gload16(B + (size_t)(rowB0 + (c1c>>2))*Kd + k0 + (c1c&3)*8, &Bs[c1c*8]);
        __syncthreads();

        short8 af[4], bfr[4];
#pragma unroll
        for (int i = 0; i < 4; i++)
            af[i] = *(const short8*)&As[(wr + i*16 + l15)*32 + l4*8];
#pragma unroll
        for (int j = 0; j < 4; j++)
            bfr[j] = *(const short8*)&Bs[(wc + j*16 + l15)*32 + l4*8];
#pragma unroll
        for (int i = 0; i < 4; i++)
#pragma unroll
            for (int j = 0; j < 4; j++)
                acc[i][j] = __builtin_amdgcn_mfma_f32_16x16x32_bf16(
                    af[i], bfr[j], acc[i][j], 0, 0, 0);
    }

    // C/D layout: col = lane&15, row = (lane>>4)*4 + reg  [m89-verified]
#pragma unroll
    for (int i = 0; i < 4; i++)
#pragma unroll
        for (int j = 0; j < 4; j++) {
            int row0 = rowA0 + wr + i*16 + l4*4;
            int col  = rowB0 + wc + j*16 + l15;
#pragma unroll
            for (int r = 0; r < 4; r++) {
                size_t off = (size_t)(row0 + r) * N + col;
                if (Cf) Cf[off] = acc[i][j][r];
                else    Cb[off] = f2bf(acc[i][j][r]);
            }
        }
}

// ---------------------------------------------------------------------------
// RMSNorm (per 128-d head vector) + RoPE, in place on bf16.
// One wave per (s, head); lane l handles elements l and l+64.
// ---------------------------------------------------------------------------
__global__ __launch_bounds__(256) void rmsnorm_rope_bf16(
    unsigned short* __restrict__ X, const float* __restrict__ w,
    const float* __restrict__ ct, const float* __restrict__ st, int nheads)
{
    int wid  = (blockIdx.x * blockDim.x + threadIdx.x) >> 6;
    int lane = threadIdx.x & 63;
    int s = wid / nheads;
    int h = wid - s * nheads;
    unsigned short* x = X + (size_t)s * (nheads * HD) + h * HD;

    float x1 = bf2f(x[lane]);
    float x2 = bf2f(x[lane + 64]);
    float ss = x1*x1 + x2*x2;
#pragma unroll
    for (int off = 32; off > 0; off >>= 1) ss += __shfl_xor(ss, off, 64);
    float r = rsqrtf(ss * (1.0f/128.0f) + 1e-6f);
    float n1 = x1 * r * w[lane];
    float n2 = x2 * r * w[lane + 64];
    float c1 = ct[s*HD + lane],      s1 = st[s*HD + lane];
    float c2 = ct[s*HD + lane + 64], s2 = st[s*HD + lane + 64];
    x[lane]      = f2bf(n1*c1 - n2*s1);
    x[lane + 64] = f2bf(n2*c2 + n1*s2);
}

// ---------------------------------------------------------------------------
// Flash attention, bf16 MFMA, causal, GQA (4 q-heads / kv-head).
// Block = (64 q-rows, one q-head), 256 threads = 4 waves; wave w owns q-rows
// w*16..w*16+15. KV tiles of 32. QK^T: 2 n-tiles x 4 k-steps = 8 mfma/wave.
// P round-trips LDS (C-layout -> A-layout); V transposed in LDS for B-operand.
// ---------------------------------------------------------------------------
__global__ __launch_bounds__(256) void flash_mfma(
    const unsigned short* __restrict__ Q, const unsigned short* __restrict__ K,
    const unsigned short* __restrict__ V, unsigned short* __restrict__ O)
{
    const int qb = blockIdx.x, h = blockIdx.y, kvh = h >> 2;
    const int tid = threadIdx.x;
    const int w = tid >> 6, lane = tid & 63;
    const int l15 = lane & 15, l4 = lane >> 4;
    const int q0 = qb * 64;

    __shared__ unsigned short Qs[64*136];   // +8 bf16 pad: row stride 272B
    __shared__ unsigned short Ks[32*136];
    __shared__ unsigned short Vt[128*40];   // V^T [dim][kv], stride 80B
    __shared__ float          Ss[64*33];
    __shared__ unsigned short Ps[64*40];
    __shared__ float m_s[64], l_s[64], al_s[64];

    {   // load Q tile 64x128 (coalesced 16B chunks)
        const unsigned short* qg = Q + (size_t)q0 * QDIM + h * HD;
#pragma unroll
        for (int i = 0; i < 4; i++) {
            int c = tid + i * 256;
            int r = c >> 4, cg = c & 15;
            int4 v = *(const int4*)(qg + (size_t)r * QDIM + cg * 8);
            *(int4*)&Qs[r * 136 + cg * 8] = v;
        }
    }
    if (tid < 64) { m_s[tid] = -1e30f; l_s[tid] = 0.f; }

    const f32x4 zero = {0.f, 0.f, 0.f, 0.f};
    f32x4 accO[8];
#pragma unroll
    for (int j = 0; j < 8; j++) accO[j] = zero;

    const float scale = 0.08838834764831845f;   // 128^-0.5
    const int ntiles = (q0 + 64) >> 5;

    for (int t = 0; t < ntiles; t++) {
        const int c0 = t << 5;
        __syncthreads();    // prev iter done with Ks/Vt/Ps (+ Q visible after next)
        {   // stage K tile [32][128] -> Ks[32][136]
            int c = tid * 2;
            int r = c >> 4, cg = c & 15;
            const unsigned short* kg = K + (size_t)(c0 + r) * KVDIM + kvh * HD + cg * 8;
            int4 a = *(const int4*)kg;
            int4 b = *(const int4*)(kg + 8);
            *(int4*)&Ks[r * 136 + cg * 8]     = a;
            *(int4*)&Ks[r * 136 + cg * 8 + 8] = b;
        }
        {   // stage V transposed: Vt[dim][kv]; thread covers 2 rows x 8 dims
            int rp = tid & 15, cg = tid >> 4;
            const unsigned short* vg = V + (size_t)(c0 + 2*rp) * KVDIM + kvh * HD + cg * 8;
            union { int4 v; unsigned short s[8]; } ua, ub;
            ua.v = *(const int4*)vg;
            ub.v = *(const int4*)(vg + KVDIM);
#pragma unroll
            for (int i = 0; i < 8; i++) {
                unsigned pack = (unsigned)ua.s[i] | ((unsigned)ub.s[i] << 16);
                *(unsigned*)&Vt[(cg*8 + i)*40 + 2*rp] = pack;
            }
        }
        __syncthreads();

        // S = Q K^T for this wave's 16 rows (2 col-tiles of 16)
        f32x4 s0 = zero, s1 = zero;
#pragma unroll
        for (int ka = 0; ka < 4; ka++) {
            short8 qa = *(const short8*)&Qs[(w*16 + l15)*136 + ka*32 + l4*8];
            short8 b0 = *(const short8*)&Ks[(l15)*136      + ka*32 + l4*8];
            short8 b1 = *(const short8*)&Ks[(16 + l15)*136 + ka*32 + l4*8];
            s0 = __builtin_amdgcn_mfma_f32_16x16x32_bf16(qa, b0, s0, 0, 0, 0);
            s1 = __builtin_amdgcn_mfma_f32_16x16x32_bf16(qa, b1, s1, 0, 0, 0);
        }
        // scale + causal mask -> Ss
#pragma unroll
        for (int r = 0; r < 4; r++) {
            int row_l = w*16 + l4*4 + r;
            int grow  = q0 + row_l;
            Ss[row_l*33 + l15]      = (c0 + l15      <= grow) ? s0[r]*scale : -1e30f;
            Ss[row_l*33 + 16 + l15] = (c0 + 16 + l15 <= grow) ? s1[r]*scale : -1e30f;
        }
        __syncthreads();

        // online softmax: one thread per q-row
        if (tid < 64) {
            int r = tid;
            float mo = m_s[r];
            float mx = mo;
            float sv[32];
#pragma unroll
            for (int c = 0; c < 32; c++) { sv[c] = Ss[r*33 + c]; mx = fmaxf(mx, sv[c]); }
            float la = 0.f;
#pragma unroll
            for (int c = 0; c < 32; c++) { float p = __expf(sv[c] - mx); sv[c] = p; la += p; }
            float alpha = __expf(mo - mx);
            m_s[r] = mx;
            l_s[r] = l_s[r] * alpha + la;
            al_s[r] = alpha;
#pragma unroll
            for (int i2 = 0; i2 < 16; i2++) {
                unsigned pack = (unsigned)f2bf(sv[2*i2]) | ((unsigned)f2bf(sv[2*i2+1]) << 16);
                *(unsigned*)&Ps[r*40 + 2*i2] = pack;
            }
        }
        __syncthreads();

        // rescale O accumulator, then PV
        f32x4 alf = *(const f32x4*)&al_s[w*16 + l4*4];
#pragma unroll
        for (int j = 0; j < 8; j++)
#pragma unroll
            for (int r = 0; r < 4; r++) accO[j][r] *= alf[r];

        short8 pf = *(const short8*)&Ps[(w*16 + l15)*40 + l4*8];
#pragma unroll
        for (int j = 0; j < 8; j++) {
            short8 vf = *(const short8*)&Vt[(j*16 + l15)*40 + l4*8];
            accO[j] = __builtin_amdgcn_mfma_f32_16x16x32_bf16(pf, vf, accO[j], 0, 0, 0);
        }
    }

    // epilogue: O = accO / l  (bf16)
    f32x4 lv = *(const f32x4*)&l_s[w*16 + l4*4];
#pragma unroll
    for (int j = 0; j < 8; j++)
#pragma unroll
        for (int r = 0; r < 4; r++) {
            int row_l = w*16 + l4*4 + r;
            int col   = j*16 + l15;
            O[(size_t)(q0 + row_l) * QDIM + h*HD + col] = f2bf(accO[j][r] / lv[r]);
        }
}

// ---------------------------------------------------------------------------
extern "C" void kernel_launch(void* const* d_in, const int* in_sizes, int n_in,
                              void* d_out, int out_size, void* d_ws, size_t ws_size,
                              hipStream_t stream)
{
    const float* hs   = (const float*)d_in[0];
    const float* cosb = (const float*)d_in[1];
    const float* sinb = (const float*)d_in[2];
    const float* Wq   = (const float*)d_in[3];
    const float* Wk   = (const float*)d_in[4];
    const float* Wv   = (const float*)d_in[5];
    const float* Wo   = (const float*)d_in[6];
    const float* qw   = (const float*)d_in[7];
    const float* kw   = (const float*)d_in[8];
    float* out = (float*)d_out;

    // Workspace layout (bytes), peak ~79.7 MB with aliasing:
    //   [hsB 10.49M][WqB 20.97M][WkB 5.24M][WvB 5.24M][WoB 20.97M][QB 16.78M]
    //   KB/VB alias dead WqB region after Q-proj; CB aliases WqB tail + WkB.
    char* ws = (char*)d_ws;
    unsigned short* hsB = (unsigned short*)(ws);
    unsigned short* WqB = (unsigned short*)(ws + 10485760);
    unsigned short* WkB = (unsigned short*)(ws + 31457280);
    unsigned short* WvB = (unsigned short*)(ws + 36700160);
    unsigned short* WoB = (unsigned short*)(ws + 41943040);
    unsigned short* QB  = (unsigned short*)(ws + 62914560);
    unsigned short* KB  = (unsigned short*)(ws + 10485760);  // alias WqB (dead after Q-proj)
    unsigned short* VB  = (unsigned short*)(ws + 14680064);
    unsigned short* CB  = (unsigned short*)(ws + 18874368);  // alias WqB tail + WkB (dead)

    // fp32 -> bf16 converts
    {
        int n4;
        n4 = S_LEN*HID/4;  cvt_f32_bf16<<<(n4+255)/256, 256, 0, stream>>>(hs, hsB, n4);
        n4 = QDIM*HID/4;   cvt_f32_bf16<<<(n4+255)/256, 256, 0, stream>>>(Wq, WqB, n4);
        n4 = KVDIM*HID/4;  cvt_f32_bf16<<<(n4+255)/256, 256, 0, stream>>>(Wk, WkB, n4);
        n4 = KVDIM*HID/4;  cvt_f32_bf16<<<(n4+255)/256, 256, 0, stream>>>(Wv, WvB, n4);
        n4 = HID*QDIM/4;   cvt_f32_bf16<<<(n4+255)/256, 256, 0, stream>>>(Wo, WoB, n4);
    }

    // projections (bf16 out)
    gemm_bf16<<<dim3(QDIM/128,  S_LEN/128), 256, 0, stream>>>(hsB, WqB, nullptr, QB, QDIM,  HID);
    gemm_bf16<<<dim3(KVDIM/128, S_LEN/128), 256, 0, stream>>>(hsB, WkB, nullptr, KB, KVDIM, HID);
    gemm_bf16<<<dim3(KVDIM/128, S_LEN/128), 256, 0, stream>>>(hsB, WvB, nullptr, VB, KVDIM, HID);

    // norm + rope (in place, bf16)
    rmsnorm_rope_bf16<<<S_LEN*NH/4,  256, 0, stream>>>(QB, qw, cosb, sinb, NH);
    rmsnorm_rope_bf16<<<S_LEN*NKV/4, 256, 0, stream>>>(KB, kw, cosb, sinb, NKV);

    // attention
    flash_mfma<<<dim3(S_LEN/64, NH), 256, 0, stream>>>(QB, KB, VB, CB);

    // output projection (fp32 out)
    gemm_bf16<<<dim3(HID/128, S_LEN/128), 256, 0, stream>>>(CB, WoB, out, nullptr, HID, QDIM);
}